// Round 3
// baseline (1349.513 us; speedup 1.0000x reference)
//
#include <hip/hip_runtime.h>

// Problem constants
constexpr int Cc   = 256;               // channels
constexpr int Kc   = 1024;              // codebook size
constexpr int NT   = 64;                // rows per main block
constexpr int KT   = 64;                // codes per LDS tile
constexpr int NLOC = 16 * 56 * 56;      // 50176
constexpr int NB   = 2;
constexpr int NTILES = NLOC / NT;       // 784
constexpr int NTOT = NB * NLOC;         // 100352
constexpr long long ZQV = (long long)NB * Cc * NLOC;
constexpr int MAIN_BLOCKS = NB * NTILES; // 1568

// f32 square with a compiler barrier: numpy rounds x*x to f32 BEFORE summing;
// prevent hipcc -ffp-contract from fusing the square into the following add.
__device__ __forceinline__ float sqf(float x) {
    float s = x * x;
    asm("" : "+v"(s));
    return s;
}

// ---------------------------------------------------------------------------
// numpy pairwise sum of squares, n=256 contiguous-in-'step' elements:
//   two halves of 128; each half: r[0..7]=sq(a[0..7]); 15x r[j]+=sq(a[8i+j]);
//   combine ((r0+r1)+(r2+r3))+((r4+r5)+(r6+r7)); then half0+half1.
// ---------------------------------------------------------------------------
template <typename Loader>
__device__ __forceinline__ float pw256_sq(Loader ld)
{
    float half[2];
    #pragma unroll
    for (int h = 0; h < 2; ++h) {
        float r[8];
        #pragma unroll
        for (int j = 0; j < 8; ++j) r[j] = sqf(ld(h * 128 + j));
        #pragma unroll
        for (int i = 8; i < 128; i += 8)
            #pragma unroll
            for (int j = 0; j < 8; ++j) r[j] += sqf(ld(h * 128 + i + j));
        half[h] = ((r[0] + r[1]) + (r[2] + r[3])) + ((r[4] + r[5]) + (r[6] + r[7]));
    }
    return half[0] + half[1];
}

// Kernel 1: esq[k] = numpy-pairwise f32 sum of key[k,:]**2
__global__ void esq_pw(const float* __restrict__ key, float* __restrict__ esq)
{
    int k = blockIdx.x * 256 + threadIdx.x;
    if (k < Kc) {
        const float* a = key + (size_t)k * Cc;
        esq[k] = pw256_sq([&](int c) { return a[c]; });
    }
}

// Kernel 2: zsq[p] = numpy-pairwise f32 sum of z_flat[p,:]**2  (channel stride NLOC)
__global__ void zsq_pw(const float* __restrict__ z, float* __restrict__ zsq)
{
    int p = blockIdx.x * 256 + threadIdx.x;   // global row
    int b = p / NLOC, loc = p - b * NLOC;
    const float* a = z + (size_t)b * Cc * NLOC + loc;
    zsq[p] = pw256_sq([&](int c) { return a[(size_t)c * NLOC]; });
}

// ---------------------------------------------------------------------------
// Kernel 3: main — replicate numpy f32 distance + argmin (first occurrence)
//   m[i,k]  = ascending-c sequential f32 FMA chain (OpenBLAS sgemm order)
//   d[i,k]  = f32( f32(zsq[i] + esq[k]) - 2*m )
// Tiled: 64 rows x 64 codes per LDS tile, 4x4 register tile per thread.
// ---------------------------------------------------------------------------
__global__ __launch_bounds__(256, 1)
void vq_main(const float* __restrict__ z, const float* __restrict__ key,
             const float* __restrict__ val, const float* __restrict__ esq,
             const float* __restrict__ zsq,
             float* __restrict__ out, double* __restrict__ partial)
{
    __shared__ float zt[Cc][NT];         // 64 KB z tile transposed [c][n]
    __shared__ float et[Cc][KT + 4];     // 68 KB code tile transposed [c][k]
    __shared__ float redv_s[NT][16];
    __shared__ int   redi_s[NT][16];
    __shared__ int   idx_sh[NT];
    __shared__ double wred[4];

    const int tid = threadIdx.x;
    const int blk = blockIdx.x;
    const int b   = blk / NTILES;
    const int n0  = (blk % NTILES) * NT;

    const float* zb = z + (size_t)b * Cc * NLOC;

    for (int i = tid; i < Cc * NT; i += 256) {
        int c = i >> 6, n = i & (NT - 1);
        zt[c][n] = zb[(size_t)c * NLOC + n0 + n];
    }

    const int tk = tid & 15;
    const int tn = tid >> 4;

    float zsq_r[4];
    #pragma unroll
    for (int a = 0; a < 4; ++a)
        zsq_r[a] = zsq[b * NLOC + n0 + tn * 4 + a];

    float bestv[4] = {3.4e38f, 3.4e38f, 3.4e38f, 3.4e38f};
    int   besti[4] = {0, 0, 0, 0};

    for (int kt = 0; kt < Kc; kt += KT) {
        __syncthreads();
        for (int i = tid; i < Cc * KT; i += 256) {
            int kk = i >> 8, c = i & 255;
            et[c][kk] = key[(size_t)(kt + kk) * Cc + c];
        }
        __syncthreads();

        float acc[4][4];
        #pragma unroll
        for (int a = 0; a < 4; ++a)
            #pragma unroll
            for (int q = 0; q < 4; ++q) acc[a][q] = 0.0f;

        for (int c = 0; c < Cc; ++c) {      // ascending c: sequential FMA chain per (row,code)
            float4 zv = *reinterpret_cast<const float4*>(&zt[c][tn * 4]);
            float4 ev = *reinterpret_cast<const float4*>(&et[c][tk * 4]);
            float za[4] = {zv.x, zv.y, zv.z, zv.w};
            float ea[4] = {ev.x, ev.y, ev.z, ev.w};
            #pragma unroll
            for (int a = 0; a < 4; ++a)
                #pragma unroll
                for (int q = 0; q < 4; ++q)
                    acc[a][q] = fmaf(za[a], ea[q], acc[a][q]);
        }

        #pragma unroll
        for (int q = 0; q < 4; ++q) {       // ascending k within thread
            int kg = kt + tk * 4 + q;
            float e2 = esq[kg];
            #pragma unroll
            for (int a = 0; a < 4; ++a) {
                float t = zsq_r[a] + e2;            // f32 add (numpy broadcast add)
                float d = fmaf(-2.0f, acc[a][q], t); // == f32(t - 2*m), 2*m exact
                if (d < bestv[a]) { bestv[a] = d; besti[a] = kg; }
            }
        }
    }

    __syncthreads();
    #pragma unroll
    for (int a = 0; a < 4; ++a) {
        redv_s[tn * 4 + a][tk] = bestv[a];
        redi_s[tn * 4 + a][tk] = besti[a];
    }
    __syncthreads();

    if (tid < NT) {
        float bv = redv_s[tid][0];
        int   bi = redi_s[tid][0];
        for (int t = 1; t < 16; ++t) {
            float v = redv_s[tid][t];
            int  ii = redi_s[tid][t];
            if (v < bv || (v == bv && ii < bi)) { bv = v; bi = ii; }  // global first-occurrence
        }
        idx_sh[tid] = bi;
        out[ZQV + (long long)b * NLOC + n0 + tid] = (float)bi;
    }
    __syncthreads();

    // gather z_q_value (bit-exact copies) + f64 loss accumulation
    double lacc = 0.0;
    for (int i = tid; i < Cc * NT; i += 256) {
        int c = i >> 6, n = i & (NT - 1);
        int id = idx_sh[n];
        out[((size_t)b * Cc + c) * NLOC + n0 + n] = val[(size_t)id * Cc + c];
        double diff = (double)key[(size_t)id * Cc + c] - (double)zt[c][n];
        lacc = fma(diff, diff, lacc);
    }
    for (int off = 32; off > 0; off >>= 1) lacc += __shfl_down(lacc, off);
    if ((tid & 63) == 0) wred[tid >> 6] = lacc;
    __syncthreads();
    if (tid == 0) partial[blk] = wred[0] + wred[1] + wred[2] + wred[3];
}

// Kernel 4: loss = 1.25 * sum / (NTOT*C)   (loss tolerance ~2.5% — f64 is plenty)
__global__ void fin_kernel(const double* __restrict__ partial, float* __restrict__ out_loss)
{
    __shared__ double sh[256];
    double s = 0.0;
    for (int i = threadIdx.x; i < MAIN_BLOCKS; i += 256) s += partial[i];
    sh[threadIdx.x] = s;
    __syncthreads();
    for (int st = 128; st > 0; st >>= 1) {
        if (threadIdx.x < st) sh[threadIdx.x] += sh[threadIdx.x + st];
        __syncthreads();
    }
    if (threadIdx.x == 0)
        out_loss[0] = (float)(1.25 * sh[0] / (double)((long long)NTOT * Cc));
}

// ---------------------------------------------------------------------------
extern "C" void kernel_launch(void* const* d_in, const int* in_sizes, int n_in,
                              void* d_out, int out_size, void* d_ws, size_t ws_size,
                              hipStream_t stream)
{
    const float* z   = (const float*)d_in[0];
    const float* key = (const float*)d_in[1];
    const float* val = (const float*)d_in[2];
    float* out = (float*)d_out;

    double* partial = (double*)d_ws;                 // 1568 f64 (8B-aligned first)
    float*  esq     = (float*)(partial + MAIN_BLOCKS); // 1024 f32
    float*  zsq     = esq + Kc;                      // 100352 f32  (total ~418 KB)

    hipLaunchKernelGGL(esq_pw, dim3((Kc + 255) / 256), dim3(256), 0, stream, key, esq);
    hipLaunchKernelGGL(zsq_pw, dim3(NTOT / 256), dim3(256), 0, stream, z, zsq);
    hipLaunchKernelGGL(vq_main, dim3(MAIN_BLOCKS), dim3(256), 0, stream,
                       z, key, val, esq, zsq, out, partial);
    hipLaunchKernelGGL(fin_kernel, dim3(1), dim3(256), 0, stream, partial, out + ZQV + NTOT);
}

// Round 4
// 933.817 us; speedup vs baseline: 1.4452x; 1.4452x over previous
//
#include <hip/hip_runtime.h>

// Problem constants
constexpr int Cc   = 256;               // channels
constexpr int Kc   = 1024;              // codebook size
constexpr int NT   = 64;                // rows per main block
constexpr int KT   = 64;                // codes per k-tile
constexpr int CB   = 64;                // c-chunk per staged phase
constexpr int NLOC = 16 * 56 * 56;      // 50176
constexpr int NB   = 2;
constexpr int NTILES = NLOC / NT;       // 784
constexpr int NTOT = NB * NLOC;         // 100352
constexpr long long ZQV = (long long)NB * Cc * NLOC;
constexpr int MAIN_BLOCKS = NB * NTILES; // 1568

// f32 square with a compiler barrier: numpy rounds x*x to f32 BEFORE summing;
// prevent hipcc -ffp-contract from fusing the square into the following add.
__device__ __forceinline__ float sqf(float x) {
    float s = x * x;
    asm("" : "+v"(s));
    return s;
}

// numpy pairwise sum of squares, n=256: two halves of 128, 8 accumulators
// stride-8 each, tree-combine — exact numpy order.
template <typename Loader>
__device__ __forceinline__ float pw256_sq(Loader ld)
{
    float half[2];
    #pragma unroll
    for (int h = 0; h < 2; ++h) {
        float r[8];
        #pragma unroll
        for (int j = 0; j < 8; ++j) r[j] = sqf(ld(h * 128 + j));
        #pragma unroll
        for (int i = 8; i < 128; i += 8)
            #pragma unroll
            for (int j = 0; j < 8; ++j) r[j] += sqf(ld(h * 128 + i + j));
        half[h] = ((r[0] + r[1]) + (r[2] + r[3])) + ((r[4] + r[5]) + (r[6] + r[7]));
    }
    return half[0] + half[1];
}

__global__ void esq_pw(const float* __restrict__ key, float* __restrict__ esq)
{
    int k = blockIdx.x * 256 + threadIdx.x;
    if (k < Kc) {
        const float* a = key + (size_t)k * Cc;
        esq[k] = pw256_sq([&](int c) { return a[c]; });
    }
}

__global__ void zsq_pw(const float* __restrict__ z, float* __restrict__ zsq)
{
    int p = blockIdx.x * 256 + threadIdx.x;
    int b = p / NLOC, loc = p - b * NLOC;
    const float* a = z + (size_t)b * Cc * NLOC + loc;
    zsq[p] = pw256_sq([&](int c) { return a[(size_t)c * NLOC]; });
}

// ---------------------------------------------------------------------------
// Main kernel: numpy-exact f32 distances + first-occurrence argmin.
// c-chunked LDS staging (34 KB total) -> 4 blocks/CU (was 1 at 143 KB).
// acc chain: ascending c across chunks == identical fmaf sequence as before.
// ---------------------------------------------------------------------------
__global__ __launch_bounds__(256, 4)
void vq_main(const float* __restrict__ z, const float* __restrict__ key,
             const float* __restrict__ val, const float* __restrict__ esq,
             const float* __restrict__ zsq,
             float* __restrict__ out, double* __restrict__ partial)
{
    __shared__ float zt[CB][NT];                           // 16 KB  [c][n]
    __shared__ __align__(16) char et_raw[CB * (KT + 4) * 4]; // 17.4 KB [c][k] (pad 4)
    __shared__ int    idx_sh[NT];
    __shared__ double wred[4];

    float (*et)[KT + 4] = reinterpret_cast<float (*)[KT + 4]>(et_raw);

    const int tid = threadIdx.x;
    const int l   = tid & 63;        // lane
    const int w   = tid >> 6;        // wave
    const int blk = blockIdx.x;
    const int b   = blk / NTILES;
    const int n0  = (blk % NTILES) * NT;
    const float* zb = z + (size_t)b * Cc * NLOC;

    const int tk = tid & 15;         // code group (4 codes)
    const int tn = tid >> 4;         // row group (4 rows)

    float zsq_r[4];
    #pragma unroll
    for (int a = 0; a < 4; ++a)
        zsq_r[a] = zsq[b * NLOC + n0 + tn * 4 + a];

    float bestv[4] = {3.4e38f, 3.4e38f, 3.4e38f, 3.4e38f};
    int   besti[4] = {0, 0, 0, 0};

    for (int kt = 0; kt < Kc; kt += KT) {
        float acc[4][4];
        #pragma unroll
        for (int a = 0; a < 4; ++a)
            #pragma unroll
            for (int q = 0; q < 4; ++q) acc[a][q] = 0.0f;

        for (int cc0 = 0; cc0 < Cc; cc0 += CB) {
            __syncthreads();   // previous phase's tiles fully consumed

            // --- et stage: float4 global reads (16 codes x 64B per wave),
            //     scalar LDS writes spread across all 32 banks (<=2-way) ---
            {
                int kk = (l >> 2) | (w << 4);                        // 0..63
                const float4* src = reinterpret_cast<const float4*>(
                    key + (size_t)(kt + kk) * Cc + cc0);
                #pragma unroll
                for (int it2 = 0; it2 < 4; ++it2) {
                    int gc = (l & 3) | (it2 << 2);                   // 0..15
                    float4 v = src[gc];
                    et[4 * gc + 0][kk] = v.x;
                    et[4 * gc + 1][kk] = v.y;
                    et[4 * gc + 2][kk] = v.z;
                    et[4 * gc + 3][kk] = v.w;
                }
            }
            // --- zt stage: float4 global reads + b128 LDS writes, conflict-free ---
            {
                int gn = l & 15;                                     // n-granule
                #pragma unroll
                for (int it2 = 0; it2 < 4; ++it2) {
                    int c = (l >> 4) | (w << 2) | (it2 << 4);        // 0..63
                    const float4 v = *reinterpret_cast<const float4*>(
                        zb + (size_t)(cc0 + c) * NLOC + n0 + 4 * gn);
                    *reinterpret_cast<float4*>(&zt[c][4 * gn]) = v;
                }
            }
            __syncthreads();

            // --- compute: ascending c, sequential fmaf chain per (row,code) ---
            for (int c = 0; c < CB; ++c) {
                float4 zv = *reinterpret_cast<const float4*>(&zt[c][tn * 4]);
                float4 ev = *reinterpret_cast<const float4*>(&et[c][tk * 4]);
                float za[4] = {zv.x, zv.y, zv.z, zv.w};
                float ea[4] = {ev.x, ev.y, ev.z, ev.w};
                #pragma unroll
                for (int a = 0; a < 4; ++a)
                    #pragma unroll
                    for (int q = 0; q < 4; ++q)
                        acc[a][q] = fmaf(za[a], ea[q], acc[a][q]);
            }
        }

        // d = f32( f32(zsq + esq) - 2*m ), ascending k within thread
        #pragma unroll
        for (int q = 0; q < 4; ++q) {
            int kg = kt + tk * 4 + q;
            float e2 = esq[kg];
            #pragma unroll
            for (int a = 0; a < 4; ++a) {
                float t = zsq_r[a] + e2;
                float d = fmaf(-2.0f, acc[a][q], t);
                if (d < bestv[a]) { bestv[a] = d; besti[a] = kg; }
            }
        }
    }

    __syncthreads();   // et region dead -> alias for argmin reduction
    float (*redv_s)[16] = reinterpret_cast<float (*)[16]>(et_raw);
    int   (*redi_s)[16] = reinterpret_cast<int   (*)[16]>(et_raw + NT * 16 * 4);

    #pragma unroll
    for (int a = 0; a < 4; ++a) {
        redv_s[tn * 4 + a][tk] = bestv[a];
        redi_s[tn * 4 + a][tk] = besti[a];
    }
    __syncthreads();

    if (tid < NT) {
        float bv = redv_s[tid][0];
        int   bi = redi_s[tid][0];
        for (int t = 1; t < 16; ++t) {
            float v = redv_s[tid][t];
            int  ii = redi_s[tid][t];
            if (v < bv || (v == bv && ii < bi)) { bv = v; bi = ii; }
        }
        idx_sh[tid] = bi;
        out[ZQV + (long long)b * NLOC + n0 + tid] = (float)bi;
    }
    __syncthreads();

    // gather z_q_value (bit-exact copies) + f64 loss (z re-read from global)
    double lacc = 0.0;
    for (int i = tid; i < Cc * NT; i += 256) {
        int c = i >> 6, n = i & (NT - 1);
        int id = idx_sh[n];
        out[((size_t)b * Cc + c) * NLOC + n0 + n] = val[(size_t)id * Cc + c];
        double diff = (double)key[(size_t)id * Cc + c]
                    - (double)zb[(size_t)c * NLOC + n0 + n];
        lacc = fma(diff, diff, lacc);
    }
    for (int off = 32; off > 0; off >>= 1) lacc += __shfl_down(lacc, off);
    if ((tid & 63) == 0) wred[tid >> 6] = lacc;
    __syncthreads();
    if (tid == 0) partial[blk] = wred[0] + wred[1] + wred[2] + wred[3];
}

__global__ void fin_kernel(const double* __restrict__ partial, float* __restrict__ out_loss)
{
    __shared__ double sh[256];
    double s = 0.0;
    for (int i = threadIdx.x; i < MAIN_BLOCKS; i += 256) s += partial[i];
    sh[threadIdx.x] = s;
    __syncthreads();
    for (int st = 128; st > 0; st >>= 1) {
        if (threadIdx.x < st) sh[threadIdx.x] += sh[threadIdx.x + st];
        __syncthreads();
    }
    if (threadIdx.x == 0)
        out_loss[0] = (float)(1.25 * sh[0] / (double)((long long)NTOT * Cc));
}

// ---------------------------------------------------------------------------
extern "C" void kernel_launch(void* const* d_in, const int* in_sizes, int n_in,
                              void* d_out, int out_size, void* d_ws, size_t ws_size,
                              hipStream_t stream)
{
    const float* z   = (const float*)d_in[0];
    const float* key = (const float*)d_in[1];
    const float* val = (const float*)d_in[2];
    float* out = (float*)d_out;

    double* partial = (double*)d_ws;                   // 1568 f64
    float*  esq     = (float*)(partial + MAIN_BLOCKS); // 1024 f32
    float*  zsq     = esq + Kc;                        // 100352 f32

    hipLaunchKernelGGL(esq_pw, dim3((Kc + 255) / 256), dim3(256), 0, stream, key, esq);
    hipLaunchKernelGGL(zsq_pw, dim3(NTOT / 256), dim3(256), 0, stream, z, zsq);
    hipLaunchKernelGGL(vq_main, dim3(MAIN_BLOCKS), dim3(256), 0, stream,
                       z, key, val, esq, zsq, out, partial);
    hipLaunchKernelGGL(fin_kernel, dim3(1), dim3(256), 0, stream, partial, out + ZQV + NTOT);
}